// Round 2
// 249.319 us; speedup vs baseline: 1.0001x; 1.0001x over previous
//
#include <hip/hip_runtime.h>

// RBF layer, algebraically collapsed:
//   out[n,o] = Bo[o] - x2[n]*S1[o] + 2 * sum_d x[n,d] * M[d,o]
// where (all tiny, precomputed per launch from the constant inputs):
//   s[d]  = relu(sigma[d]);  w[k] = relu(width[k]);  Wr = relu(output_weights)
//   M[d,o]  = s[d] * sum_k center[k,d]*w[k]*Wr[1+k,o]          [256 x 128]
//   S1[o]   = sum_k w[k]*Wr[1+k,o]
//   c2[k]   = sum_d center[k,d]^2 * s[d]
//   Bo[o]   = Wr[0,o] + sum_k Wr[1+k,o] - sum_k c2[k]*w[k]*Wr[1+k,o]
//   x2[n]   = sum_d s[d]*x[n,d]^2   (fp32, computed in the main kernel)
// Main GEMM term uses bf16 MFMA 16x16x32 (abs-err ~0.1 vs threshold ~1075).
//
// Evidence log:
//  R2: nontemporal stores -> +10% WRITE_SIZE (write amplification). Plain stores.
//  R3: __launch_bounds__(512,3) forced VGPR cap ~170 -> raw[]/a[] spilled to
//      scratch (+290 MB FETCH, +300 MB WRITE, 340 us). LDS staging itself was
//      correct (absmax unchanged, 0 bank conflicts).
//  R4: same structure, (512,2) cap -> no spill; one-shot grid. 249 us.
//  R5: rocprof top-5 = harness poison fills (79.7us each) -> rbf_main < 80us,
//      i.e. ~2.6 TB/s vs ~6 TB/s roofline. (512,2) = 1 block/CU (natural VGPR
//      >170 per R3), phases serialize. Restructure for VGPR<=128 -> 2 blocks/CU
//      (LDS-capped): global_load_lds staging (no stg[] regs), loads folded into
//      convert loop (no raw[16]), native bf16 cvt (cvt_pk), shuffle hoist
//      32->4, column-permuted Mfrag so epilogue is 8 coalesced dwordx4 stores
//      per wave instead of 32 scalar stores + 32 bpermutes.
//  R6: infra failure (container acquisition failed twice; no result) ->
//      resubmitting R5 unchanged.

typedef short  short8 __attribute__((ext_vector_type(8)));
typedef __bf16 bf16x8 __attribute__((ext_vector_type(8)));
typedef float  f32x4  __attribute__((ext_vector_type(4)));

#define N_ 131072
#define D_ 256
#define K_ 256
#define O_ 128

__device__ __forceinline__ unsigned short f2bf_bits(float f) {
  unsigned u = __builtin_bit_cast(unsigned, f);
  u += 0x7fffu + ((u >> 16) & 1u);   // round-to-nearest-even
  return (unsigned short)(u >> 16);
}

__device__ __forceinline__ float relu(float v) { return v > 0.f ? v : 0.f; }

// ---- Precompute kernel: 65 blocks x 256 threads ---------------------------
// Blocks 0..63: one (ks,ot) B-fragment tile of M each (32 d x 16 o), with
// ww[k][oc]=relu(w)*relu(Wr) and cen[k][dc] staged in LDS so the 256-deep
// k-loop is pure LDS. Block 64: c2 -> LDS, then Bo[o], S1[o].
// Output-column permutation (R5): fragment column oc of tile ot holds actual
// output column  o = (ot>>2)*64 + oc*4 + (ot&3)  so that in the main kernel
// lane m's 8 per-ot accumulator values are the contiguous cols m*4..m*4+3 and
// 64+m*4..64+m*4+3  -> vectorized coalesced stores.
__global__ __launch_bounds__(256) void rbf_pre(
    const float* __restrict__ center, const float* __restrict__ sigma,
    const float* __restrict__ width,  const float* __restrict__ W,
    short* __restrict__ Mfrag, float* __restrict__ Bo, float* __restrict__ S1)
{
  const int tid = threadIdx.x;
  if (blockIdx.x < 64) {
    const int ot = blockIdx.x & 7;
    const int ks = blockIdx.x >> 3;
    __shared__ float ww[K_][16];   // 16 KB
    __shared__ float cen[K_][32];  // 32 KB
    const int ocol = (ot >> 2) * 64 + (tid & 15) * 4 + (ot & 3); // permuted o
#pragma unroll
    for (int i = 0; i < 16; ++i) {
      const int k  = i * 16 + (tid >> 4);
      const int oc = tid & 15;
      ww[k][oc] = relu(width[k]) * relu(W[(1 + k) * O_ + ocol]);
    }
#pragma unroll
    for (int i = 0; i < 32; ++i) {
      const int k  = i * 8 + (tid >> 5);
      const int dc = tid & 31;
      cen[k][dc] = center[k * D_ + ks * 32 + dc];
    }
    __syncthreads();
    const int j   = tid & 7;
    const int lf  = tid >> 3;              // 0..31 == MFMA lane field
    const int oc  = lf & 15;
    const int dc1 = (lf >> 4) * 8 + j;     // 0..15
    float a1 = 0.f, a2 = 0.f;
#pragma unroll 8
    for (int k = 0; k < K_; ++k) {
      const float w = ww[k][oc];
      a1 = fmaf(cen[k][dc1],      w, a1);
      a2 = fmaf(cen[k][dc1 + 16], w, a2);
    }
    const int e1 = blockIdx.x * 512 + tid;
    const int d1 = ks * 32 + dc1;
    Mfrag[e1]       = (short)f2bf_bits(a1 * relu(sigma[d1]));
    Mfrag[e1 + 256] = (short)f2bf_bits(a2 * relu(sigma[d1 + 16]));
  } else {
    __shared__ float c2s[K_];
    {
      // 4 independent chains, f32x4 loads: latency-tolerant.
      const f32x4* cr = (const f32x4*)(center + tid * D_);
      const f32x4* sr = (const f32x4*)sigma;
      f32x4 acc = {0.f, 0.f, 0.f, 0.f};
#pragma unroll 8
      for (int d4 = 0; d4 < D_ / 4; ++d4) {
        const f32x4 c = cr[d4];
        const f32x4 s = sr[d4];
#pragma unroll
        for (int e = 0; e < 4; ++e) acc[e] = fmaf(c[e] * c[e], relu(s[e]), acc[e]);
      }
      c2s[tid] = (acc[0] + acc[1]) + (acc[2] + acc[3]);
    }
    __syncthreads();
    if (tid < O_) {
      const int o = tid;
      float s1 = 0.f, sum = 0.f, c2w = 0.f;
#pragma unroll 4
      for (int k = 0; k < K_; ++k) {
        const float w  = relu(width[k]);
        const float wr = relu(W[(1 + k) * O_ + o]);
        s1  = fmaf(w, wr, s1);
        sum += wr;
        c2w = fmaf(c2s[k] * w, wr, c2w);
      }
      Bo[o] = relu(W[o]) + sum - c2w;
      S1[o] = s1;
    }
  }
}

// ---- Main kernel: 1024 blocks x 512 threads (8 waves), one tile/wave ------
// (512,4): VGPR cap 128 -> 2 blocks/CU (LDS = 2x64 KiB of the 160 KiB),
// 16 waves/CU; the two resident blocks run phase-offset so one block's x-load
// burst overlaps the other's MFMA/store phase. Mfrag staged via
// global_load_lds width=16 (wave-linear dest, zero staging VGPRs/VALU).
__global__ __launch_bounds__(512, 4) void rbf_main(
    const float* __restrict__ x, const float* __restrict__ sigma,
    const short* __restrict__ Mfrag, const float* __restrict__ Bo,
    const float* __restrict__ S1, float* __restrict__ out)
{
  __shared__ short8 Blds[4096];                 // 64 KiB, B-fragment layout
  const int tid  = threadIdx.x;
  const int lane = tid & 63;
  const int wv   = tid >> 6;                    // 0..7
  const int m    = lane & 15;                   // A row / C col within tile
  const int q    = lane >> 4;                   // quad
  const long rowBase = ((long)blockIdx.x * 8 + wv) * 16;

  // Async-stage Mfrag -> LDS (64 KiB, L2-hot). Dest is wave-uniform base +
  // lane*16B, exactly our lane-contiguous layout. Issued first: these are
  // oldest in the vmcnt queue and retire from L2 before the x-load waits bite.
  {
    const short8* gsrc = (const short8*)Mfrag + wv * 64 + lane;
    short8* ldst = &Blds[wv * 64];
#pragma unroll
    for (int i = 0; i < 8; ++i) {
      __builtin_amdgcn_global_load_lds(
          (const __attribute__((address_space(1))) unsigned int*)(gsrc + i * 512),
          (__attribute__((address_space(3))) unsigned int*)(ldst + i * 512),
          16, 0, 0);
    }
  }

  // Load x, convert to bf16 A-fragments (native cvt -> v_cvt_pk_bf16_f32),
  // accumulate fp32 x2 along the way. Compiler pipelines the loads under the
  // 128-VGPR cap (no raw[16] burst array held live).
  const float* xr = x + (rowBase + m) * D_ + q * 8;
  const float* sp = sigma + q * 8;
  bf16x8 a[8];
  float x2 = 0.f;
#pragma unroll
  for (int ks = 0; ks < 8; ++ks) {
    const f32x4 v0  = *(const f32x4*)(xr + ks * 32);
    const f32x4 v1  = *(const f32x4*)(xr + ks * 32 + 4);
    const f32x4 sv0 = *(const f32x4*)(sp + ks * 32);      // L1-hot (1 KB)
    const f32x4 sv1 = *(const f32x4*)(sp + ks * 32 + 4);
    bf16x8 av;
#pragma unroll
    for (int e = 0; e < 4; ++e) {
      const float sa = relu(sv0[e]);
      const float sb = relu(sv1[e]);
      x2 = fmaf(sa * v0[e], v0[e], x2);
      x2 = fmaf(sb * v1[e], v1[e], x2);
      av[e]     = (__bf16)v0[e];
      av[e + 4] = (__bf16)v1[e];
    }
    a[ks] = av;
  }
  // Reduce x2 across the 4 lanes holding the same row, then broadcast the 4
  // row-values this lane's C-fragment needs (hoisted: was 32 bpermutes in the
  // ot loop, loop-invariant -> 4).
  x2 += __shfl_xor(x2, 16);
  x2 += __shfl_xor(x2, 32);
  float x2b[4];
#pragma unroll
  for (int r = 0; r < 4; ++r) x2b[r] = __shfl(x2, q * 4 + r);

  // Per-lane bias vectors for the permuted columns (L1-hot, 1 KB total).
  const f32x4 bo0 = *(const f32x4*)(Bo + m * 4);
  const f32x4 bo1 = *(const f32x4*)(Bo + 64 + m * 4);
  const f32x4 s10 = *(const f32x4*)(S1 + m * 4);
  const f32x4 s11 = *(const f32x4*)(S1 + 64 + m * 4);

  f32x4 accs[8];
#pragma unroll
  for (int ot = 0; ot < 8; ++ot) accs[ot] = (f32x4){0.f, 0.f, 0.f, 0.f};

  __syncthreads();                              // Blds ready (vmcnt drained)

#pragma unroll
  for (int ks = 0; ks < 8; ++ks) {
    const bf16x8 aa = a[ks];
#pragma unroll
    for (int ot = 0; ot < 8; ++ot) {
      const bf16x8 bb =
          __builtin_bit_cast(bf16x8, Blds[(ks * 8 + ot) * 64 + lane]);
      accs[ot] = __builtin_amdgcn_mfma_f32_16x16x32_bf16(aa, bb, accs[ot], 0, 0, 0);
    }
  }

  // Epilogue: lane m owns cols m*4..m*4+3 (ot=0..3) and 64+m*4.. (ot=4..7) of
  // rows q*4+r -> two dwordx4 stores per row, fully coalesced (lanes 0..15
  // cover 256 B contiguous per q-group).
  float* orow = out + (rowBase + q * 4) * (long)O_ + m * 4;
#pragma unroll
  for (int r = 0; r < 4; ++r) {
    const float x2r = x2b[r];
    f32x4 lo, hi;
#pragma unroll
    for (int j = 0; j < 4; ++j) {
      lo[j] = fmaf(2.f, accs[j][r],     fmaf(-x2r, s10[j], bo0[j]));
      hi[j] = fmaf(2.f, accs[j + 4][r], fmaf(-x2r, s11[j], bo1[j]));
    }
    *(f32x4*)(orow + (long)r * O_)      = lo;
    *(f32x4*)(orow + (long)r * O_ + 64) = hi;
  }
}

extern "C" void kernel_launch(void* const* d_in, const int* in_sizes, int n_in,
                              void* d_out, int out_size, void* d_ws, size_t ws_size,
                              hipStream_t stream) {
  (void)in_sizes; (void)n_in; (void)out_size; (void)ws_size;
  const float* x      = (const float*)d_in[0];
  const float* center = (const float*)d_in[1];
  const float* sigma  = (const float*)d_in[2];
  const float* width  = (const float*)d_in[3];
  const float* W      = (const float*)d_in[4];
  float* out = (float*)d_out;

  short* Mfrag = (short*)d_ws;                       // 64 KiB
  float* Bo    = (float*)((char*)d_ws + 65536);      // 512 B
  float* S1    = (float*)((char*)d_ws + 66048);      // 512 B

  hipLaunchKernelGGL(rbf_pre, dim3(65), dim3(256), 0, stream,
                     center, sigma, width, W, Mfrag, Bo, S1);
  hipLaunchKernelGGL(rbf_main, dim3(1024), dim3(512), 0, stream,
                     x, sigma, Mfrag, Bo, S1, out);
}